// Round 5
// baseline (378.968 us; speedup 1.0000x reference)
//
#include <hip/hip_runtime.h>

// QuaternionLinear as one 4096^3 bf16 GEMM (B^T layout).
// Round 5: BARRIER-FREE K-loop. One wave per block, wave-private
// double-buffered LDS staging (16 KB), manual s_waitcnt vmcnt(8) so 8
// prefetch loads always stay in flight (hipBLASLt idiom; never vmcnt(0)
// until the last iteration). No __syncthreads in the entire GEMM.
// R4's verified XOR swizzle retained (source-chunk permutation).

typedef __bf16 bf16x8 __attribute__((ext_vector_type(8)));
typedef float floatx4 __attribute__((ext_vector_type(4)));

constexpr int M = 4096;   // batch
constexpr int N = 4096;   // out_f * 4
constexpr int K = 4096;   // in_f * 4
constexpr int BK = 32;
constexpr int ITERS = K / BK;   // 128

constexpr int CVT_BLOCKS = (M * K / 8) / 256;        // 8192: x fp32 -> bf16
constexpr int EXP_BLOCKS = (1024 * 1024 / 2) / 256;  // 2048: w -> signed Wbig

// s_waitcnt simm16: vm[3:0] | exp<<4 | lgkm<<8 | vm[5:4]<<14
#define WAIT_VM8 0x0F78   // vmcnt(8), lgkm/exp don't-care
#define WAIT_VM0 0x0F70   // vmcnt(0), lgkm/exp don't-care

// ---------- fused prep: x -> A (bf16), w -> Wbig (sign-expanded bf16) ----------
// Wbig rows (c order) per quaternion w=(r,i,j,k):
//   d=0: [+r,-i,-j,-k]  d=1: [+i,+r,+k,-j]  d=2: [+j,-k,+r,+i]  d=3: [+k,+j,-i,+r]
__global__ void prep_kernel(const float* __restrict__ x, const float* __restrict__ w,
                            __bf16* __restrict__ A, __bf16* __restrict__ Wb) {
    const int b = blockIdx.x;
    if (b < CVT_BLOCKS) {
        const size_t i = (size_t)b * 256 + threadIdx.x;   // 8 elems/thread
        const float4* xp = (const float4*)x;
        float4 a = xp[2 * i];
        float4 c = xp[2 * i + 1];
        bf16x8 v;
        v[0] = (__bf16)a.x; v[1] = (__bf16)a.y; v[2] = (__bf16)a.z; v[3] = (__bf16)a.w;
        v[4] = (__bf16)c.x; v[5] = (__bf16)c.y; v[6] = (__bf16)c.z; v[7] = (__bf16)c.w;
        *(bf16x8*)(A + 8 * i) = v;
    } else {
        const int idx = (b - CVT_BLOCKS) * 256 + threadIdx.x;  // quaternion PAIR index
        const int o  = idx >> 9;
        const int ip = (idx & 511) * 2;
        float4 q0 = ((const float4*)w)[o * 1024 + ip];
        float4 q1 = ((const float4*)w)[o * 1024 + ip + 1];
        __bf16* base = Wb + (size_t)(o * 4) * K + ip * 4;
        bf16x8 r;
        r[0] = (__bf16)q0.x; r[1] = (__bf16)(-q0.y); r[2] = (__bf16)(-q0.z); r[3] = (__bf16)(-q0.w);
        r[4] = (__bf16)q1.x; r[5] = (__bf16)(-q1.y); r[6] = (__bf16)(-q1.z); r[7] = (__bf16)(-q1.w);
        *(bf16x8*)(base) = r;
        r[0] = (__bf16)q0.y; r[1] = (__bf16)q0.x; r[2] = (__bf16)q0.w; r[3] = (__bf16)(-q0.z);
        r[4] = (__bf16)q1.y; r[5] = (__bf16)q1.x; r[6] = (__bf16)q1.w; r[7] = (__bf16)(-q1.z);
        *(bf16x8*)(base + (size_t)K) = r;
        r[0] = (__bf16)q0.z; r[1] = (__bf16)(-q0.w); r[2] = (__bf16)q0.x; r[3] = (__bf16)q0.y;
        r[4] = (__bf16)q1.z; r[5] = (__bf16)(-q1.w); r[6] = (__bf16)q1.x; r[7] = (__bf16)q1.y;
        *(bf16x8*)(base + (size_t)2 * K) = r;
        r[0] = (__bf16)q0.w; r[1] = (__bf16)q0.z; r[2] = (__bf16)(-q0.y); r[3] = (__bf16)q0.x;
        r[4] = (__bf16)q1.w; r[5] = (__bf16)q1.z; r[6] = (__bf16)(-q1.y); r[7] = (__bf16)q1.x;
        *(bf16x8*)(base + (size_t)3 * K) = r;
    }
}

// ---------- async global->LDS, 16B per lane ----------
__device__ __forceinline__ void gload_lds16(const __bf16* g, __bf16* l) {
    __builtin_amdgcn_global_load_lds(
        (const __attribute__((address_space(1))) void*)g,
        (__attribute__((address_space(3))) void*)l, 16, 0, 0);
}

// ---------- GEMM: one wave per 64x64 C-tile, barrier-free pipeline ----------
__global__ __launch_bounds__(64) void qgemm_kernel(const __bf16* __restrict__ A,
                                                   const __bf16* __restrict__ B,
                                                   const float* __restrict__ bias,
                                                   float* __restrict__ C) {
    __shared__ __bf16 Ab[2][64][BK];   // 2 x 4 KB
    __shared__ __bf16 Bb[2][64][BK];   // 2 x 4 KB

    const int lane = threadIdx.x;      // one wave

    // XCD-aware remap of 64x64 tile grid: xcd = bid&7 owns an 8(M)x64(N)
    // slab, ordered in 8x8 squares (K-synchronized streaming keeps the
    // live k-slice of A/B panels in per-XCD L2).
    const int bid = blockIdx.x;
    const int xcd = bid & 7;
    const int q   = bid >> 3;          // 0..511
    const int sq  = q >> 6;            // 0..7  (N super-column)
    const int r   = q & 63;
    const int ty  = xcd * 8 + (r >> 3);
    const int tx  = sq * 8 + (r & 7);
    const int bm = ty * 64;
    const int bn = tx * 64;

    // staging: issue i covers rows [i*16, i*16+16), row = lane>>2, 16B slot = lane&3.
    // XOR source swizzle: source chunk = slot ^ ((row>>1)&3)
    //   => LDS chunk c of row r holds global chunk c ^ ((r>>1)&3)
    const int srow = lane >> 2;
    const int sc   = (lane & 3) ^ ((lane >> 3) & 3);

    const __bf16* ag[4];
    const __bf16* bg[4];
#pragma unroll
    for (int i = 0; i < 4; ++i) {
        ag[i] = A + (size_t)(bm + i * 16 + srow) * K + sc * 8;
        bg[i] = B + (size_t)(bn + i * 16 + srow) * K + sc * 8;
    }

    floatx4 acc[4][4] = {};

    const int fl  = lane & 15;                   // m (A) / n (B) index within 16
    const int fq  = lane >> 4;                   // global 16B chunk 0..3
    const int fco = (fq ^ ((fl >> 1) & 3)) * 8;  // swizzled LDS element offset

    auto issue = [&](int buf, int k) {
        const int off = k * BK;
#pragma unroll
        for (int i = 0; i < 4; ++i) gload_lds16(ag[i] + off, &Ab[buf][i * 16][0]);
#pragma unroll
        for (int i = 0; i < 4; ++i) gload_lds16(bg[i] + off, &Bb[buf][i * 16][0]);
    };

    auto compute = [&](int buf) {
        bf16x8 af[4], bfr[4];
#pragma unroll
        for (int t = 0; t < 4; ++t)
            af[t] = *(const bf16x8*)&Ab[buf][t * 16 + fl][fco];
#pragma unroll
        for (int t = 0; t < 4; ++t)
            bfr[t] = *(const bf16x8*)&Bb[buf][t * 16 + fl][fco];
#pragma unroll
        for (int mt = 0; mt < 4; ++mt)
#pragma unroll
            for (int nt = 0; nt < 4; ++nt)
                acc[mt][nt] = __builtin_amdgcn_mfma_f32_16x16x32_bf16(
                    af[mt], bfr[nt], acc[mt][nt], 0, 0, 0);
    };

    issue(0, 0);
    issue(1, 1);

#pragma unroll 2
    for (int k = 0; k < ITERS - 2; ++k) {
        __builtin_amdgcn_s_waitcnt(WAIT_VM8);   // oldest 8 (this iter's buf) done
        compute(k & 1);
        issue(k & 1, k + 2);                    // refill just-consumed buffer
    }
    __builtin_amdgcn_s_waitcnt(WAIT_VM8);       // k = ITERS-2, buf 0
    compute(0);
    __builtin_amdgcn_s_waitcnt(WAIT_VM0);       // k = ITERS-1, buf 1 (last: drain)
    compute(1);

    // epilogue: C/D layout col = lane&15, row = (lane>>4)*4 + reg  (verified R1)
#pragma unroll
    for (int mt = 0; mt < 4; ++mt) {
        const int row = bm + mt * 16 + fq * 4;
#pragma unroll
        for (int nt = 0; nt < 4; ++nt) {
            const int col = bn + nt * 16 + fl;
            const float bv = bias[col];
            float* cp = C + (size_t)row * N + col;
#pragma unroll
            for (int rg = 0; rg < 4; ++rg)
                cp[(size_t)rg * N] = acc[mt][nt][rg] + bv;
        }
    }
}

extern "C" void kernel_launch(void* const* d_in, const int* in_sizes, int n_in,
                              void* d_out, int out_size, void* d_ws, size_t ws_size,
                              hipStream_t stream) {
    const float* x    = (const float*)d_in[0];   // (4096,1024,4) fp32
    const float* w    = (const float*)d_in[1];   // (1024,1024,4) fp32
    const float* bias = (const float*)d_in[2];   // (1024,4) fp32
    float* out = (float*)d_out;                  // (4096,1024,4) fp32

    __bf16* Abf  = (__bf16*)d_ws;                                   // 32 MB
    __bf16* Wbig = (__bf16*)((char*)d_ws + (size_t)M * K * 2);      // 32 MB

    prep_kernel<<<CVT_BLOCKS + EXP_BLOCKS, 256, 0, stream>>>(x, w, Abf, Wbig);

    qgemm_kernel<<<(M / 64) * (N / 64), 64, 0, stream>>>(Abf, Wbig, bias, out);
}

// Round 6
// 284.831 us; speedup vs baseline: 1.3305x; 1.3305x over previous
//
#include <hip/hip_runtime.h>

// QuaternionLinear as one 4096^3 bf16 GEMM (B^T layout).
// Round 6: R4 block structure (128x128 tile, 4 waves, BK=32, XOR swizzle,
// XCD remap) + 3-stage cyclic LDS pipeline with ONE raw s_barrier per
// K-iteration and per-wave s_waitcnt vmcnt(4) — prefetch loads stay in
// flight across the barrier (never vmcnt(0) until the final iteration).
// WAR safety: iter k reads buf k%3, issues DMA for iter k+2 into (k+2)%3;
// any wave past iter-k's barrier implies all waves finished iter-(k-1)
// ds_reads, so rewriting that buffer is safe. asm "memory" clobber on the
// barrier pins ds_reads on the correct side.

typedef __bf16 bf16x8 __attribute__((ext_vector_type(8)));
typedef float floatx4 __attribute__((ext_vector_type(4)));

constexpr int M = 4096;   // batch
constexpr int N = 4096;   // out_f * 4
constexpr int K = 4096;   // in_f * 4
constexpr int BM = 128, BN = 128, BK = 32;

constexpr int CVT_BLOCKS = (M * K / 8) / 256;        // 8192: x fp32 -> bf16
constexpr int EXP_BLOCKS = (1024 * 1024 / 2) / 256;  // 2048: w -> signed Wbig

// s_waitcnt simm16: vm[3:0] | exp<<4 | lgkm<<8 | vm[5:4]<<14
#define WAIT_VM4 0x0F74   // vmcnt(4)
#define WAIT_VM0 0x0F70   // vmcnt(0)
#define BARRIER() asm volatile("s_barrier" ::: "memory")

// ---------- fused prep: x -> A (bf16), w -> Wbig (sign-expanded bf16) ----------
// Wbig rows (c order) per quaternion w=(r,i,j,k):
//   d=0: [+r,-i,-j,-k]  d=1: [+i,+r,+k,-j]  d=2: [+j,-k,+r,+i]  d=3: [+k,+j,-i,+r]
__global__ void prep_kernel(const float* __restrict__ x, const float* __restrict__ w,
                            __bf16* __restrict__ A, __bf16* __restrict__ Wb) {
    const int b = blockIdx.x;
    if (b < CVT_BLOCKS) {
        const size_t i = (size_t)b * 256 + threadIdx.x;   // 8 elems/thread
        const float4* xp = (const float4*)x;
        float4 a = xp[2 * i];
        float4 c = xp[2 * i + 1];
        bf16x8 v;
        v[0] = (__bf16)a.x; v[1] = (__bf16)a.y; v[2] = (__bf16)a.z; v[3] = (__bf16)a.w;
        v[4] = (__bf16)c.x; v[5] = (__bf16)c.y; v[6] = (__bf16)c.z; v[7] = (__bf16)c.w;
        *(bf16x8*)(A + 8 * i) = v;
    } else {
        const int idx = (b - CVT_BLOCKS) * 256 + threadIdx.x;  // quaternion PAIR index
        const int o  = idx >> 9;
        const int ip = (idx & 511) * 2;
        float4 q0 = ((const float4*)w)[o * 1024 + ip];
        float4 q1 = ((const float4*)w)[o * 1024 + ip + 1];
        __bf16* base = Wb + (size_t)(o * 4) * K + ip * 4;
        bf16x8 r;
        r[0] = (__bf16)q0.x; r[1] = (__bf16)(-q0.y); r[2] = (__bf16)(-q0.z); r[3] = (__bf16)(-q0.w);
        r[4] = (__bf16)q1.x; r[5] = (__bf16)(-q1.y); r[6] = (__bf16)(-q1.z); r[7] = (__bf16)(-q1.w);
        *(bf16x8*)(base) = r;
        r[0] = (__bf16)q0.y; r[1] = (__bf16)q0.x; r[2] = (__bf16)q0.w; r[3] = (__bf16)(-q0.z);
        r[4] = (__bf16)q1.y; r[5] = (__bf16)q1.x; r[6] = (__bf16)q1.w; r[7] = (__bf16)(-q1.z);
        *(bf16x8*)(base + (size_t)K) = r;
        r[0] = (__bf16)q0.z; r[1] = (__bf16)(-q0.w); r[2] = (__bf16)q0.x; r[3] = (__bf16)q0.y;
        r[4] = (__bf16)q1.z; r[5] = (__bf16)(-q1.w); r[6] = (__bf16)q1.x; r[7] = (__bf16)q1.y;
        *(bf16x8*)(base + (size_t)2 * K) = r;
        r[0] = (__bf16)q0.w; r[1] = (__bf16)q0.z; r[2] = (__bf16)(-q0.y); r[3] = (__bf16)q0.x;
        r[4] = (__bf16)q1.w; r[5] = (__bf16)q1.z; r[6] = (__bf16)(-q1.y); r[7] = (__bf16)q1.x;
        *(bf16x8*)(base + (size_t)3 * K) = r;
    }
}

// ---------- async global->LDS, 16B per lane ----------
__device__ __forceinline__ void gload_lds16(const __bf16* g, __bf16* l) {
    __builtin_amdgcn_global_load_lds(
        (const __attribute__((address_space(1))) void*)g,
        (__attribute__((address_space(3))) void*)l, 16, 0, 0);
}

// ---------- GEMM: C[M][N] = A[M][K] * B[N][K]^T + bias[N] ----------
__global__ void qgemm_kernel(const __bf16* __restrict__ A,
                             const __bf16* __restrict__ B,
                             const float* __restrict__ bias,
                             float* __restrict__ C) {
    __shared__ __bf16 As[3][BM][BK];   // 3 x 8 KB
    __shared__ __bf16 Bs[3][BN][BK];   // 3 x 8 KB  (48 KB total -> 3 blocks/CU)

    const int tid  = threadIdx.x;
    const int wave = tid >> 6;
    const int lane = tid & 63;

    // XCD-aware remap (R4): xcd = bid&7 owns a 16x8 region, M fastest.
    const int bid = blockIdx.x;
    const int xcd = bid & 7;
    const int q   = bid >> 3;                       // 0..127
    const int ty  = (xcd >> 2) * 16 + (q & 15);     // 0..31  (M tile)
    const int tx  = (xcd & 3) * 8 + (q >> 4);       // 0..31  (N tile)
    const int bm = ty * BM;
    const int bn = tx * BN;

    const int wm = (wave & 1) * 64;   // wave's C-subtile origin
    const int wn = (wave >> 1) * 64;

    // staging: each issue = 16 rows x 64B. row = lane>>2, 16B slot = lane&3.
    // XOR source swizzle: source chunk = slot ^ ((row>>1)&3)
    //   => LDS chunk c of row r holds global chunk c ^ ((r>>1)&3)
    const int ldrow = lane >> 2;
    const int sc    = (lane & 3) ^ ((lane >> 3) & 3);
    const int ldcol = sc * 8;

    const __bf16* ag0 = A + (size_t)(bm + wave * 16 + ldrow) * K + ldcol;
    const __bf16* ag1 = ag0 + (size_t)64 * K;
    const __bf16* bg0 = B + (size_t)(bn + wave * 16 + ldrow) * K + ldcol;
    const __bf16* bg1 = bg0 + (size_t)64 * K;

    floatx4 acc[4][4] = {};

    const int fl  = lane & 15;                      // m (A) / n (B) index within 16
    const int fq  = lane >> 4;                      // global 16B chunk 0..3
    const int fco = (fq ^ ((fl >> 1) & 3)) * 8;     // swizzled LDS element offset

    auto issue = [&](int b, int k) {
        const int off = k * BK;
        gload_lds16(ag0 + off, &As[b][wave * 16][0]);       // wave-uniform base
        gload_lds16(ag1 + off, &As[b][64 + wave * 16][0]);
        gload_lds16(bg0 + off, &Bs[b][wave * 16][0]);
        gload_lds16(bg1 + off, &Bs[b][64 + wave * 16][0]);
    };

    // step: ds_read frags from buffer br, optionally issue iter k+2 into bw, MFMA.
    auto step = [&](int k, int br, int bw, bool doi) {
        bf16x8 af[4], bfr[4];
#pragma unroll
        for (int t = 0; t < 4; ++t)
            af[t] = *(const bf16x8*)&As[br][wm + t * 16 + fl][fco];
#pragma unroll
        for (int t = 0; t < 4; ++t)
            bfr[t] = *(const bf16x8*)&Bs[br][wn + t * 16 + fl][fco];
        if (doi) issue(bw, k + 2);
#pragma unroll
        for (int mt = 0; mt < 4; ++mt)
#pragma unroll
            for (int nt = 0; nt < 4; ++nt)
                acc[mt][nt] = __builtin_amdgcn_mfma_f32_16x16x32_bf16(
                    af[mt], bfr[nt], acc[mt][nt], 0, 0, 0);
    };

    issue(0, 0);
    issue(1, 1);

    for (int k = 0; k < 126; k += 3) {              // 42 triples
        __builtin_amdgcn_s_waitcnt(WAIT_VM4);       // my iter-k loads landed
        BARRIER();                                  // everyone's landed; k+1 still in flight
        step(k, 0, 2, true);
        __builtin_amdgcn_s_waitcnt(WAIT_VM4);
        BARRIER();
        step(k + 1, 1, 0, true);
        __builtin_amdgcn_s_waitcnt(WAIT_VM4);
        BARRIER();
        step(k + 2, 2, 1, true);
    }
    __builtin_amdgcn_s_waitcnt(WAIT_VM4);           // k=126: 127's loads stay in flight
    BARRIER();
    step(126, 0, 0, false);
    __builtin_amdgcn_s_waitcnt(WAIT_VM0);           // k=127: final drain
    BARRIER();
    step(127, 1, 0, false);

    // epilogue: C/D layout col = lane&15, row = (lane>>4)*4 + reg  (verified R1)
#pragma unroll
    for (int mt = 0; mt < 4; ++mt) {
        const int row = bm + wm + mt * 16 + fq * 4;
#pragma unroll
        for (int nt = 0; nt < 4; ++nt) {
            const int col = bn + wn + nt * 16 + fl;
            const float bv = bias[col];
            float* cp = C + (size_t)row * N + col;
#pragma unroll
            for (int r = 0; r < 4; ++r)
                cp[(size_t)r * N] = acc[mt][nt][r] + bv;
        }
    }
}

extern "C" void kernel_launch(void* const* d_in, const int* in_sizes, int n_in,
                              void* d_out, int out_size, void* d_ws, size_t ws_size,
                              hipStream_t stream) {
    const float* x    = (const float*)d_in[0];   // (4096,1024,4) fp32
    const float* w    = (const float*)d_in[1];   // (1024,1024,4) fp32
    const float* bias = (const float*)d_in[2];   // (1024,4) fp32
    float* out = (float*)d_out;                  // (4096,1024,4) fp32

    __bf16* Abf  = (__bf16*)d_ws;                                   // 32 MB
    __bf16* Wbig = (__bf16*)((char*)d_ws + (size_t)M * K * 2);      // 32 MB

    prep_kernel<<<CVT_BLOCKS + EXP_BLOCKS, 256, 0, stream>>>(x, w, Abf, Wbig);

    qgemm_kernel<<<1024, 256, 0, stream>>>(Abf, Wbig, bias, out);
}